// Round 3
// baseline (264.617 us; speedup 1.0000x reference)
//
#include <hip/hip_runtime.h>

#define DIM 64
#define EDGE_CHUNK 2048              // edges per histogram/place block
#define GEMM_ROWS 128                // rows per gemm block
#define SCAN_TILE 1024               // nodes per local-scan block

// ws layout (256-aligned):
// flag | deg[N] | rowptr[N] | cur[N] | dinv[N] | bsum[128] | boff[128] |
// srcs[E] | h[N*64] bf16
//
// Pipeline (all serial, all uncontended):
//   K0 init: zero deg, detect int64 edges
//   K1 deghist: deg[d]++ over raw dst (atomics spread over 100k addrs)
//   K2 scan_local: per-1024-node exclusive scan -> rowptr(local), bsum, dinv
//   K3 scan_block: exclusive scan of 98 block sums -> boff
//   K4 scan_final: rowptr += boff; cur = rowptr
//   K5 gemm: h = bf16((x @ W^T) * dinv[row])      (pre-scaled by dinv[src])
//   K6 place: pos = cur[dst]++; srcs[pos] = src   (true dst-sorted CSR)
//   K7 aggregate: register fp32 accumulate per dst run — NO atomics, NO LDS acc

__device__ __forceinline__ unsigned short f2bf(float f) {
    unsigned u = __float_as_uint(f);
    u += 0x7fffu + ((u >> 16) & 1u);     // round-to-nearest-even
    return (unsigned short)(u >> 16);
}
__device__ __forceinline__ float bf2f(unsigned short u) {
    return __uint_as_float((unsigned)u << 16);
}

// K0: zero deg + int64-vs-int32 edge detect.
__global__ __launch_bounds__(256) void init_kernel(const int* __restrict__ ei32,
                                                   int* __restrict__ flag,
                                                   int* __restrict__ deg, int N) {
    int gid = threadIdx.x + blockIdx.x * 256;
    int stride = gridDim.x * 256;
    for (int i = gid; i < N; i += stride) deg[i] = 0;
    if (blockIdx.x == 0) {
        __shared__ int any_nz;
        int t = threadIdx.x;
        if (t == 0) any_nz = 0;
        __syncthreads();
        int v = ei32[2 * t + 1];     // odd int32 words: all-zero iff nonneg int64 data
        if (v != 0) atomicOr(&any_nz, 1);
        __syncthreads();
        if (t == 0) *flag = (any_nz == 0) ? 1 : 0;
    }
}

// K1: in-degree histogram from raw dst list.  1M no-return atomics spread
// over 100k addresses (6250 lines) — no per-line hotspot.
__global__ __launch_bounds__(256) void deghist_kernel(const void* __restrict__ ei,
                                                      const int* __restrict__ flagp,
                                                      int* __restrict__ deg, int E) {
    int is64 = *flagp;
    int tid = threadIdx.x;
    int i0 = blockIdx.x * EDGE_CHUNK;
    int dd[EDGE_CHUNK / 256];
#pragma unroll
    for (int k = 0; k < EDGE_CHUNK / 256; ++k) {
        int i = i0 + k * 256 + tid;
        dd[k] = -1;
        if (i < E)
            dd[k] = is64 ? (int)((const long long*)ei)[(long long)i + E]
                         : ((const int*)ei)[i + E];
    }
#pragma unroll
    for (int k = 0; k < EDGE_CHUNK / 256; ++k)
        if (dd[k] >= 0) atomicAdd(&deg[dd[k]], 1);
}

// K2: per-block (1024 nodes) exclusive scan of deg -> rowptr (block-local),
// block sum -> bsum, and dinv = rsqrt(deg+1).
__global__ __launch_bounds__(256) void scan_local_kernel(const int* __restrict__ deg,
                                                         int* __restrict__ rowptr,
                                                         float* __restrict__ dinv,
                                                         int* __restrict__ bsum, int N) {
    __shared__ int ts[256];
    int tid = threadIdx.x;
    int base = blockIdx.x * SCAN_TILE + tid * 4;
    int d0 = 0, d1 = 0, d2 = 0, d3 = 0;
    if (base + 3 < N) {
        int4 v = *(const int4*)(deg + base);
        d0 = v.x; d1 = v.y; d2 = v.z; d3 = v.w;
    } else {
        if (base + 0 < N) d0 = deg[base + 0];
        if (base + 1 < N) d1 = deg[base + 1];
        if (base + 2 < N) d2 = deg[base + 2];
        if (base + 3 < N) d3 = deg[base + 3];
    }
    int tsum = d0 + d1 + d2 + d3;
    ts[tid] = tsum;
    __syncthreads();
#pragma unroll
    for (int s = 1; s < 256; s <<= 1) {
        int t = (tid >= s) ? ts[tid - s] : 0;
        __syncthreads();
        ts[tid] += t;
        __syncthreads();
    }
    int excl = ts[tid] - tsum;
    if (tid == 255) bsum[blockIdx.x] = ts[255];
    if (base + 0 < N) { rowptr[base + 0] = excl; dinv[base + 0] = rsqrtf((float)(d0 + 1)); }
    excl += d0;
    if (base + 1 < N) { rowptr[base + 1] = excl; dinv[base + 1] = rsqrtf((float)(d1 + 1)); }
    excl += d1;
    if (base + 2 < N) { rowptr[base + 2] = excl; dinv[base + 2] = rsqrtf((float)(d2 + 1)); }
    excl += d2;
    if (base + 3 < N) { rowptr[base + 3] = excl; dinv[base + 3] = rsqrtf((float)(d3 + 1)); }
}

// K3: exclusive scan of the (<=128) block sums.
__global__ __launch_bounds__(128) void scan_block_kernel(const int* __restrict__ bsum,
                                                         int* __restrict__ boff, int nb) {
    __shared__ int s[128];
    int tid = threadIdx.x;
    int v = (tid < nb) ? bsum[tid] : 0;
    s[tid] = v;
    __syncthreads();
#pragma unroll
    for (int st = 1; st < 128; st <<= 1) {
        int t = (tid >= st) ? s[tid - st] : 0;
        __syncthreads();
        s[tid] += t;
        __syncthreads();
    }
    if (tid < nb) boff[tid] = s[tid] - v;
}

// K4: finalize absolute rowptr and seed the place cursors.
__global__ __launch_bounds__(256) void scan_final_kernel(int* __restrict__ rowptr,
                                                         const int* __restrict__ boff,
                                                         int* __restrict__ cur, int N) {
    int n = threadIdx.x + blockIdx.x * 256;
    if (n < N) {
        int r = rowptr[n] + boff[n >> 10];
        rowptr[n] = r;
        cur[n] = r;
    }
}

// K5: h[r] = bf16( (x[r] @ W^T) * dinv[r] ).  128x64 tile, thread = 4 rows x 8
// cols, Xs staged in two 32-k halves (16 KB) + Wt (16 KB) = 32 KB LDS.
__global__ __launch_bounds__(256, 4) void gemm_kernel(const float* __restrict__ x,
                                                      const float* __restrict__ W,
                                                      const float* __restrict__ dinv,
                                                      unsigned short* __restrict__ h, int N) {
    __shared__ float Wt[64 * 64];               // Wt[k*64+c]
    __shared__ float Xs[32 * GEMM_ROWS];        // Xs[kl*128+r]
    int tid = threadIdx.x;
    int row0 = blockIdx.x * GEMM_ROWS;
    int nrows = min(GEMM_ROWS, N - row0);
#pragma unroll
    for (int t = 0; t < 16; ++t) {
        int i = t * 256 + tid;
        Wt[i] = W[((i & 63) << 6) | (i >> 6)];   // Wt[k*64+c] = W[c*64+k]
    }
    const float* xbase = x + (size_t)row0 * DIM;
    int tc = tid & 7;
    int tr = tid >> 3;
    float acc[4][8] = {};
#pragma unroll
    for (int kh = 0; kh < 2; ++kh) {
        __syncthreads();   // kh=0: Wt visible; kh=1: prior compute done reading Xs
#pragma unroll
        for (int t = 0; t < 16; ++t) {
            int i = t * 256 + tid;                 // i = kl*128 + r
            int r = i & (GEMM_ROWS - 1);
            int k = (i >> 7) + 32 * kh;
            Xs[i] = (r < nrows) ? xbase[r * DIM + k] : 0.0f;
        }
        __syncthreads();
#pragma unroll 4
        for (int kl = 0; kl < 32; ++kl) {
            int k = kl + 32 * kh;
            float4 xv = *(const float4*)&Xs[kl * GEMM_ROWS + 4 * tr];
            float4 w0 = *(const float4*)&Wt[k * 64 + 8 * tc];
            float4 w1 = *(const float4*)&Wt[k * 64 + 8 * tc + 4];
            const float* xp = (const float*)&xv;
            const float* wp0 = (const float*)&w0;
            const float* wp1 = (const float*)&w1;
#pragma unroll
            for (int i = 0; i < 4; ++i) {
#pragma unroll
                for (int j = 0; j < 4; ++j) {
                    acc[i][j] = fmaf(xp[i], wp0[j], acc[i][j]);
                    acc[i][4 + j] = fmaf(xp[i], wp1[j], acc[i][4 + j]);
                }
            }
        }
    }
#pragma unroll
    for (int i = 0; i < 4; ++i) {
        int r = 4 * tr + i;
        if (r < nrows) {
            int g = row0 + r;
            float dv = dinv[g];
            ushort4 o0, o1;
            o0.x = f2bf(acc[i][0] * dv); o0.y = f2bf(acc[i][1] * dv);
            o0.z = f2bf(acc[i][2] * dv); o0.w = f2bf(acc[i][3] * dv);
            o1.x = f2bf(acc[i][4] * dv); o1.y = f2bf(acc[i][5] * dv);
            o1.z = f2bf(acc[i][6] * dv); o1.w = f2bf(acc[i][7] * dv);
            ushort4* hp = (ushort4*)(h + (size_t)g * DIM + 8 * tc);
            hp[0] = o0;
            hp[1] = o1;
        }
    }
}

// K6: counting-sort placement.  atomic-with-return queues are ~10 deep per
// node address (vs 489 per bin-line before) — uncontended.
__global__ __launch_bounds__(256) void place_kernel(const void* __restrict__ ei,
                                                    const int* __restrict__ flagp,
                                                    int* __restrict__ cur,
                                                    int* __restrict__ srcs, int E) {
    int is64 = *flagp;
    int tid = threadIdx.x;
    int i0 = blockIdx.x * EDGE_CHUNK;
    int ss[EDGE_CHUNK / 256], dd[EDGE_CHUNK / 256];
#pragma unroll
    for (int k = 0; k < EDGE_CHUNK / 256; ++k) {
        int i = i0 + k * 256 + tid;
        dd[k] = -1;
        if (i < E) {
            if (is64) {
                ss[k] = (int)((const long long*)ei)[i];
                dd[k] = (int)((const long long*)ei)[(long long)i + E];
            } else {
                ss[k] = ((const int*)ei)[i];
                dd[k] = ((const int*)ei)[i + E];
            }
        }
    }
#pragma unroll
    for (int k = 0; k < EDGE_CHUNK / 256; ++k) {
        if (dd[k] >= 0) {
            int pos = atomicAdd(&cur[dd[k]], 1);
            srcs[pos] = ss[k];
        }
    }
}

// K7: atomic-free aggregate.  Block = 64 dst nodes, wave = 16 dst, 64 lanes =
// 64 features.  h rows are pre-scaled by dinv[src]; accumulate in fp32
// registers over each node's contiguous CSR run.
__global__ __launch_bounds__(256) void aggregate_kernel(
    const unsigned short* __restrict__ h, const int* __restrict__ srcs,
    const int* __restrict__ rowptr, const int* __restrict__ deg,
    const float* __restrict__ dinv, const float* __restrict__ bias,
    float* __restrict__ out, int N) {
    int tid = threadIdx.x;
    int wave = tid >> 6, lane = tid & 63;
    int node0 = blockIdx.x * 64 + wave * 16;
    float bl = bias[lane];
#pragma unroll 1
    for (int t = 0; t < 16; ++t) {
        int d = node0 + t;
        if (d >= N) break;
        int rs = rowptr[d];
        int n = deg[d];
        float di = dinv[d];
        const int* sp = srcs + rs;
        float acc = 0.0f;
        int e = 0;
        for (; e + 4 <= n; e += 4) {
            int s0 = sp[e], s1 = sp[e + 1], s2 = sp[e + 2], s3 = sp[e + 3];
            float v0 = bf2f(h[(size_t)s0 * DIM + lane]);
            float v1 = bf2f(h[(size_t)s1 * DIM + lane]);
            float v2 = bf2f(h[(size_t)s2 * DIM + lane]);
            float v3 = bf2f(h[(size_t)s3 * DIM + lane]);
            acc += (v0 + v1) + (v2 + v3);
        }
        for (; e < n; ++e)
            acc += bf2f(h[(size_t)sp[e] * DIM + lane]);
        float self = bf2f(h[(size_t)d * DIM + lane]);    // pre-scaled by dinv[d]
        out[(size_t)d * DIM + lane] = (acc + self) * di + bl;
    }
}

extern "C" void kernel_launch(void* const* d_in, const int* in_sizes, int n_in,
                              void* d_out, int out_size, void* d_ws, size_t ws_size,
                              hipStream_t stream) {
    const float* x = (const float*)d_in[0];
    const void* ei = d_in[1];
    const float* W = (const float*)d_in[2];
    const float* b = (const float*)d_in[3];
    float* out = (float*)d_out;

    int N = in_sizes[0] / DIM;   // 100000
    int E = in_sizes[1] / 2;     // 1000000

    char* ws = (char*)d_ws;
    auto align256 = [](size_t v) { return (v + 255) & ~(size_t)255; };
    size_t off = 0;
    int* flag = (int*)(ws + off);      off = align256(off + 4);
    int* deg = (int*)(ws + off);       off = align256(off + (size_t)N * 4);
    int* rowptr = (int*)(ws + off);    off = align256(off + (size_t)N * 4);
    int* cur = (int*)(ws + off);       off = align256(off + (size_t)N * 4);
    float* dinv = (float*)(ws + off);  off = align256(off + (size_t)N * 4);
    int* bsum = (int*)(ws + off);      off = align256(off + 128 * 4);
    int* boff = (int*)(ws + off);      off = align256(off + 128 * 4);
    int* srcs = (int*)(ws + off);      off = align256(off + (size_t)E * 4);
    unsigned short* h = (unsigned short*)(ws + off); off = align256(off + (size_t)N * DIM * 2);

    int nchunks = (E + EDGE_CHUNK - 1) / EDGE_CHUNK;        // 489
    int nscan = (N + SCAN_TILE - 1) / SCAN_TILE;            // 98
    int gemmblocks = (N + GEMM_ROWS - 1) / GEMM_ROWS;       // 782
    int aggblocks = (N + 63) / 64;                          // 1563

    init_kernel<<<nscan, 256, 0, stream>>>((const int*)ei, flag, deg, N);
    deghist_kernel<<<nchunks, 256, 0, stream>>>(ei, flag, deg, E);
    scan_local_kernel<<<nscan, 256, 0, stream>>>(deg, rowptr, dinv, bsum, N);
    scan_block_kernel<<<1, 128, 0, stream>>>(bsum, boff, nscan);
    scan_final_kernel<<<(N + 255) / 256, 256, 0, stream>>>(rowptr, boff, cur, N);
    gemm_kernel<<<gemmblocks, 256, 0, stream>>>(x, W, dinv, h, N);
    place_kernel<<<nchunks, 256, 0, stream>>>(ei, flag, cur, srcs, E);
    aggregate_kernel<<<aggblocks, 256, 0, stream>>>(h, srcs, rowptr, deg, dinv, b, out, N);
}

// Round 4
// 194.140 us; speedup vs baseline: 1.3630x; 1.3630x over previous
//
#include <hip/hip_runtime.h>

#define DIM 64
#define BIN_SHIFT 7                  // 128 nodes per bin
#define NODES_PER_BIN 128
#define MAX_BINS 1024                // ceil(100000/128)=782 <= 1024
#define BIN_CAP 2048                 // mean 1279, sigma ~36 -> 21-sigma margin
#define CHUNK_EDGES 1024             // edges per scatter block (978 blocks -> 2x occupancy)
#define GEMM_ROWS 128                // rows per gemm block
#define FXSCALE 65536.0f             // fixed-point scale 2^16
#define FXINV (1.0f / 65536.0f)
#define FXBIAS 524288u               // 2^19 per-term bias (|v|<8 -> term >= 0)
#define MAGIC 12582912.0f            // 1.5*2^23 RNE float->int magic
#define MAGIC_I 0x4B400000u
#define GCUR_STRIDE 16               // one cacheline per bin counter (de-hotspot)
#define ACC_U64 33                   // u64 per node: 32 used + 1 pad (odd stride)

// ws layout (256-aligned):
// flag | gcur[MAX_BINS*16] | deg[N+1] | dinv[N+1] | pairs[nbins*BIN_CAP+64] | h[(N+1)*64] bf16
// h row N = zero dummy row; deg/dinv dummies unused (aggregate predicated).

__device__ __forceinline__ unsigned short f2bf(float f) {
    unsigned u = __float_as_uint(f);
    u += 0x7fffu + ((u >> 16) & 1u);     // round-to-nearest-even
    return (unsigned short)(u >> 16);
}
__device__ __forceinline__ float bf2f(unsigned short u) {
    return __uint_as_float((unsigned)u << 16);
}

// init: int64-vs-int32 edge detect, zero gcur, zero dummy h row.
__global__ __launch_bounds__(256) void init_kernel(const int* __restrict__ ei32,
                                                   int* __restrict__ flag,
                                                   int* __restrict__ gcur,
                                                   unsigned short* __restrict__ h,
                                                   int N, int nbins) {
    int gid = threadIdx.x + blockIdx.x * 256;
    int stride = gridDim.x * 256;
    for (int i = gid; i < nbins * GCUR_STRIDE; i += stride) gcur[i] = 0;
    if (blockIdx.x == 0) {
        __shared__ int any_nz;
        int t = threadIdx.x;
        if (t == 0) any_nz = 0;
        __syncthreads();
        int v = ei32[2 * t + 1];     // odd int32 words: all-zero iff nonneg int64 data
        if (v != 0) atomicOr(&any_nz, 1);
        if (t < 32) ((unsigned*)(h + (size_t)N * DIM))[t] = 0;   // dummy row
        __syncthreads();
        if (t == 0) *flag = (any_nz == 0) ? 1 : 0;
    }
}

// Pass 1: scatter packed (src<<7 | dst&127) into dst-bins.  Round-0-proven
// shape; CHUNK 1024 doubles co-resident waves, gcur strided per-line.
__global__ __launch_bounds__(256) void bin_scatter_kernel(const void* __restrict__ ei,
                                                          const int* __restrict__ flagp,
                                                          int* __restrict__ gcur,
                                                          int* __restrict__ pairs,
                                                          int E, int nbins) {
    __shared__ int h1[MAX_BINS];
    __shared__ int base[MAX_BINS];
    int tid = threadIdx.x;
    int is64 = *flagp;
    int chunk = blockIdx.x * CHUNK_EDGES;

    int ss[CHUNK_EDGES / 256], dd[CHUNK_EDGES / 256];

    for (int i = tid; i < nbins; i += 256) h1[i] = 0;
    __syncthreads();
#pragma unroll
    for (int k = 0; k < CHUNK_EDGES / 256; ++k) {
        int i = chunk + k * 256 + tid;
        if (i < E) {
            int s, d;
            if (is64) {
                s = (int)((const long long*)ei)[i];
                d = (int)((const long long*)ei)[(long long)i + E];
            } else {
                s = ((const int*)ei)[i];
                d = ((const int*)ei)[i + E];
            }
            ss[k] = s; dd[k] = d;
            atomicAdd(&h1[d >> BIN_SHIFT], 1);
        } else {
            dd[k] = -1;
        }
    }
    __syncthreads();
    for (int i = tid; i < nbins; i += 256) {
        int c = h1[i];
        base[i] = c ? (i * BIN_CAP + atomicAdd(&gcur[i * GCUR_STRIDE], c)) : 0;
        h1[i] = 0;
    }
    __syncthreads();
#pragma unroll
    for (int k = 0; k < CHUNK_EDGES / 256; ++k) {
        if (dd[k] >= 0) {
            int bin = dd[k] >> BIN_SHIFT;
            int r = atomicAdd(&h1[bin], 1);
            int pos = base[bin] + r;
            if (pos < (bin + 1) * BIN_CAP)          // overflow guard (never expected)
                pairs[pos] = (ss[k] << BIN_SHIFT) | (dd[k] & (NODES_PER_BIN - 1));
        }
    }
}

// Pass 2: per-bin degree histogram -> deg (term count for bias subtract) +
// dinv.  Bin holds ALL in-edges of its nodes.
__global__ __launch_bounds__(256) void degree_kernel(const int* __restrict__ pairs,
                                                     const int* __restrict__ gcur,
                                                     int* __restrict__ deg,
                                                     float* __restrict__ dinv, int N) {
    __shared__ int sdeg[NODES_PER_BIN];
    int b = blockIdx.x;
    int tid = threadIdx.x;
    int base = b * BIN_CAP;
    int cnt = min(gcur[b * GCUR_STRIDE], BIN_CAP);
    int node0 = b << BIN_SHIFT;
    int nn = min(NODES_PER_BIN, N - node0);
    if (tid < NODES_PER_BIN) sdeg[tid] = 0;
    __syncthreads();
    for (int i = tid; i < cnt; i += 256)
        atomicAdd(&sdeg[pairs[base + i] & (NODES_PER_BIN - 1)], 1);
    __syncthreads();
    if (tid < nn) {
        int d = sdeg[tid];
        deg[node0 + tid] = d;
        dinv[node0 + tid] = rsqrtf((float)(d + 1));   // +1 self-loop
    }
}

// h[r] = bf16( (x[r] @ W^T) * dinv[r] ).  Round-0-proven 128x64 tile.
__global__ __launch_bounds__(256, 4) void gemm_kernel(const float* __restrict__ x,
                                                      const float* __restrict__ W,
                                                      const float* __restrict__ dinv,
                                                      unsigned short* __restrict__ h, int N) {
    __shared__ float Wt[64 * 64];               // Wt[k*64+c]
    __shared__ float Xs[64 * GEMM_ROWS];        // Xs[k*128+r]
    int tid = threadIdx.x;
    int row0 = blockIdx.x * GEMM_ROWS;
    int nrows = min(GEMM_ROWS, N - row0);

#pragma unroll
    for (int t = 0; t < 16; ++t) {
        int i = t * 256 + tid;
        Wt[i] = W[((i & 63) << 6) | (i >> 6)];
    }
    const float* xbase = x + (size_t)row0 * DIM;
#pragma unroll
    for (int t = 0; t < 32; ++t) {
        int i = t * 256 + tid;
        int r = i & (GEMM_ROWS - 1);
        int k = i >> 7;
        Xs[i] = (r < nrows) ? xbase[r * DIM + k] : 0.0f;
    }
    __syncthreads();

    int tc = tid & 7;
    int tr = tid >> 3;
    float acc[4][8] = {};
#pragma unroll 4
    for (int k = 0; k < 64; ++k) {
        float4 xv = *(const float4*)&Xs[k * GEMM_ROWS + 4 * tr];
        float4 w0 = *(const float4*)&Wt[k * 64 + 8 * tc];
        float4 w1 = *(const float4*)&Wt[k * 64 + 8 * tc + 4];
        const float* xp = (const float*)&xv;
        const float* wp0 = (const float*)&w0;
        const float* wp1 = (const float*)&w1;
#pragma unroll
        for (int i = 0; i < 4; ++i) {
#pragma unroll
            for (int j = 0; j < 4; ++j) {
                acc[i][j] = fmaf(xp[i], wp0[j], acc[i][j]);
                acc[i][4 + j] = fmaf(xp[i], wp1[j], acc[i][4 + j]);
            }
        }
    }
#pragma unroll
    for (int i = 0; i < 4; ++i) {
        int r = 4 * tr + i;
        if (r < nrows) {
            int g = row0 + r;
            float dv = dinv[g];
            ushort4 o0, o1;
            o0.x = f2bf(acc[i][0] * dv); o0.y = f2bf(acc[i][1] * dv);
            o0.z = f2bf(acc[i][2] * dv); o0.w = f2bf(acc[i][3] * dv);
            o1.x = f2bf(acc[i][4] * dv); o1.y = f2bf(acc[i][5] * dv);
            o1.z = f2bf(acc[i][6] * dv); o1.w = f2bf(acc[i][7] * dv);
            ushort4* hp = (ushort4*)(h + (size_t)g * DIM + 8 * tc);
            hp[0] = o0;
            hp[1] = o1;
        }
    }
}

// Pass 3: per-bin aggregate.  h pre-scaled by dinv[src] (round-0 numerics).
// Biased fixed-point, 2 features per ds_add_u64 -> 0.5 LDS-atomic wave-instr
// per edge (was 1).  Epilogue subtracts deg*BIAS, adds self-loop + bias.
__global__ __launch_bounds__(256) void bin_aggregate_kernel(
    const unsigned short* __restrict__ h, const int* __restrict__ pairs,
    const int* __restrict__ gcur, const int* __restrict__ deg,
    const float* __restrict__ dinv,
    const float* __restrict__ bias, float* __restrict__ out, int N) {
    __shared__ unsigned long long acc[NODES_PER_BIN * ACC_U64];   // 33 KB
    int b = blockIdx.x;
    int tid = threadIdx.x;
    int base = b * BIN_CAP;
    int cnt = min(gcur[b * GCUR_STRIDE], BIN_CAP);
    int node0 = b << BIN_SHIFT;
    int nn = min(NODES_PER_BIN, N - node0);

    for (int i = tid; i < NODES_PER_BIN * ACC_U64; i += 256) acc[i] = 0ULL;
    __syncthreads();

    int wave = tid >> 6, lane = tid & 63;
    int g = lane >> 4;                 // edge slot 0..3
    int fq = lane & 15;                // features 4*fq .. 4*fq+3
    const int* pb = pairs + base;
    int dummy = N << BIN_SHIFT;        // src=N (zero row), predicated off

    for (int j0 = 32 * wave; j0 < cnt; j0 += 128) {
        int pk[8]; bool vd[8];
#pragma unroll
        for (int u = 0; u < 8; ++u) {
            int e = j0 + 4 * u + g;
            vd[u] = (e < cnt);                 // uniform per 16-lane group
            pk[u] = vd[u] ? pb[e] : dummy;
        }
        ushort4 r[8];
#pragma unroll
        for (int u = 0; u < 8; ++u)            // issue all gathers before use
            r[u] = *(const ushort4*)(h + (size_t)(pk[u] >> BIN_SHIFT) * DIM + 4 * fq);
#pragma unroll
        for (int u = 0; u < 8; ++u) {
            unsigned q0 = __float_as_uint(fmaf(bf2f(r[u].x), FXSCALE, MAGIC)) - (MAGIC_I - FXBIAS);
            unsigned q1 = __float_as_uint(fmaf(bf2f(r[u].y), FXSCALE, MAGIC)) - (MAGIC_I - FXBIAS);
            unsigned q2 = __float_as_uint(fmaf(bf2f(r[u].z), FXSCALE, MAGIC)) - (MAGIC_I - FXBIAS);
            unsigned q3 = __float_as_uint(fmaf(bf2f(r[u].w), FXSCALE, MAGIC)) - (MAGIC_I - FXBIAS);
            if (vd[u]) {
                unsigned long long* ar =
                    &acc[(pk[u] & (NODES_PER_BIN - 1)) * ACC_U64 + 2 * fq];
                atomicAdd(&ar[0], (unsigned long long)q0 | ((unsigned long long)q1 << 32));
                atomicAdd(&ar[1], (unsigned long long)q2 | ((unsigned long long)q3 << 32));
            }
        }
    }
    __syncthreads();

    // dword view: feature f of node ld lives at dword [ld*66 + f]
    const int* accd = (const int*)acc;
    for (int ld = wave; ld < nn; ld += 4) {
        int gn = node0 + ld;                                // wave-uniform
        int dgn = deg[gn];
        float di = dinv[gn];
        unsigned q = (unsigned)accd[ld * (2 * ACC_U64) + lane];
        int sfx = (int)(q - (unsigned)dgn * FXBIAS);        // remove per-term bias
        float sum = (float)sfx * FXINV;
        float self = bf2f(h[(size_t)gn * DIM + lane]);      // pre-scaled by dinv[gn]
        out[(size_t)gn * DIM + lane] = (sum + self) * di + bias[lane];
    }
}

extern "C" void kernel_launch(void* const* d_in, const int* in_sizes, int n_in,
                              void* d_out, int out_size, void* d_ws, size_t ws_size,
                              hipStream_t stream) {
    const float* x = (const float*)d_in[0];
    const void* ei = d_in[1];
    const float* W = (const float*)d_in[2];
    const float* b = (const float*)d_in[3];
    float* out = (float*)d_out;

    int N = in_sizes[0] / DIM;   // 100000
    int E = in_sizes[1] / 2;     // 1000000
    int nbins = (N + NODES_PER_BIN - 1) >> BIN_SHIFT;   // 782

    char* ws = (char*)d_ws;
    auto align256 = [](size_t v) { return (v + 255) & ~(size_t)255; };
    size_t off = 0;
    int* flag = (int*)(ws + off);              off = align256(off + 4);
    int* gcur = (int*)(ws + off);              off = align256(off + (size_t)MAX_BINS * GCUR_STRIDE * 4);
    int* deg  = (int*)(ws + off);              off = align256(off + (size_t)(N + 1) * 4);
    float* dinv = (float*)(ws + off);          off = align256(off + (size_t)(N + 1) * 4);
    int* pairs = (int*)(ws + off);             off = align256(off + ((size_t)nbins * BIN_CAP + 64) * 4);
    unsigned short* h = (unsigned short*)(ws + off); off = align256(off + (size_t)(N + 1) * DIM * 2);

    int nchunks = (E + CHUNK_EDGES - 1) / CHUNK_EDGES;       // 977
    int gemmblocks = (N + GEMM_ROWS - 1) / GEMM_ROWS;        // 782

    init_kernel<<<64, 256, 0, stream>>>((const int*)ei, flag, gcur, h, N, nbins);
    bin_scatter_kernel<<<nchunks, 256, 0, stream>>>(ei, flag, gcur, pairs, E, nbins);
    degree_kernel<<<nbins, 256, 0, stream>>>(pairs, gcur, deg, dinv, N);
    gemm_kernel<<<gemmblocks, 256, 0, stream>>>(x, W, dinv, h, N);
    bin_aggregate_kernel<<<nbins, 256, 0, stream>>>(h, pairs, gcur, deg, dinv, b, out, N);
}

// Round 5
// 178.702 us; speedup vs baseline: 1.4808x; 1.0864x over previous
//
#include <hip/hip_runtime.h>

#define DIM 64
#define BIN_SHIFT 7                  // 128 nodes per bin
#define NODES_PER_BIN 128
#define MAX_BINS 1024                // ceil(100000/128)=782 <= 1024
#define BIN_CAP 2048                 // mean 1279, sigma ~36 -> 21-sigma margin
#define CHUNK_EDGES 1024             // edges per count/place block (977 blocks)
#define BSTRIDE 1024                 // cnt matrix row stride (ints); nchunks<=1024
#define GEMM_ROWS 128                // rows per gemm tile == nodes per bin
#define FXSCALE 65536.0f             // fixed-point scale 2^16
#define FXINV (1.0f / 65536.0f)
#define FXBIAS 524288u               // 2^19 per-term bias (|v|<8 -> term >= 0)
#define MAGIC 12582912.0f            // 1.5*2^23 RNE float->int magic
#define MAGIC_I 0x4B400000u
#define AGG_STRIDE 17                // u64 per node row: 16 used + 1 pad

// ws layout (256-aligned):
// cnt[MAX_BINS*BSTRIDE] | bintot[MAX_BINS] | deg[N+1] | dinv[N+1] |
// pairs[nbins*BIN_CAP+64] | h[(N+1)*64] bf16
//
// Pipeline (5 dispatches, ZERO global atomics):
//   K1 count: per-block LDS bin histogram -> cnt[bin][blk] plain stores
//   K2 scan:  per-bin exclusive prefix over blocks (in-place) + bintot
//   K3 place: base = cnt[bin][blk] (load!), LDS rank, write packed pairs
//   K4 deg_gemm: bin-degree -> dinv in LDS -> gemm epilogue scales h
//   K5 aggregate: 2 blocks/bin x 32 features, u64 biased fixed-point LDS acc

__device__ __forceinline__ unsigned short f2bf(float f) {
    unsigned u = __float_as_uint(f);
    u += 0x7fffu + ((u >> 16) & 1u);     // round-to-nearest-even
    return (unsigned short)(u >> 16);
}
__device__ __forceinline__ float bf2f(unsigned short u) {
    return __uint_as_float((unsigned)u << 16);
}

// K1: per-chunk bin histogram.  is64 probe replicated per block (first 256
// int64 odd words, L2-hot).  Output: plain scattered stores, no dependency.
__global__ __launch_bounds__(256) void count_kernel(const void* __restrict__ ei,
                                                    int* __restrict__ cnt,
                                                    int E, int nbins) {
    __shared__ int h1[MAX_BINS];
    __shared__ int s_notz;
    int tid = threadIdx.x;
    if (tid == 0) s_notz = 0;
    for (int i = tid; i < nbins; i += 256) h1[i] = 0;
    __syncthreads();
    if (((const int*)ei)[2 * tid + 1] != 0) s_notz = 1;   // benign race (same value)
    __syncthreads();
    int is64 = (s_notz == 0);

    int chunk = blockIdx.x * CHUNK_EDGES;
    int dd[CHUNK_EDGES / 256];
#pragma unroll
    for (int k = 0; k < CHUNK_EDGES / 256; ++k) {
        int i = chunk + k * 256 + tid;
        dd[k] = -1;
        if (i < E)
            dd[k] = is64 ? (int)((const long long*)ei)[(long long)i + E]
                         : ((const int*)ei)[i + E];
    }
#pragma unroll
    for (int k = 0; k < CHUNK_EDGES / 256; ++k)
        if (dd[k] >= 0) atomicAdd(&h1[dd[k] >> BIN_SHIFT], 1);
    __syncthreads();
    int blk = blockIdx.x;
    for (int i = tid; i < nbins; i += 256)
        cnt[i * BSTRIDE + blk] = h1[i];      // fire-and-forget
}

// K2: per-bin exclusive scan of cnt row (in-place) + bin total.
__global__ __launch_bounds__(256) void scan_kernel(int* __restrict__ cnt,
                                                   int* __restrict__ bintot,
                                                   int nchunks) {
    __shared__ int ts[256];
    int b = blockIdx.x;
    int tid = threadIdx.x;
    int* row = cnt + (size_t)b * BSTRIDE;
    int base4 = tid * 4;
    int v[4];
#pragma unroll
    for (int k = 0; k < 4; ++k)
        v[k] = (base4 + k < nchunks) ? row[base4 + k] : 0;
    int tsum = v[0] + v[1] + v[2] + v[3];
    ts[tid] = tsum;
    __syncthreads();
#pragma unroll
    for (int s = 1; s < 256; s <<= 1) {
        int t = (tid >= s) ? ts[tid - s] : 0;
        __syncthreads();
        ts[tid] += t;
        __syncthreads();
    }
    int excl = ts[tid] - tsum;
    if (tid == 255) bintot[b] = ts[255];
#pragma unroll
    for (int k = 0; k < 4; ++k) {
        if (base4 + k < nchunks) row[base4 + k] = excl;
        excl += v[k];
    }
}

// K3: placement.  Block's per-bin base is a LOAD from the scanned matrix —
// no atomic-return stall.  LDS rank atomics give unique slots within block.
__global__ __launch_bounds__(256) void place_kernel(const void* __restrict__ ei,
                                                    const int* __restrict__ cnt,
                                                    int* __restrict__ pairs,
                                                    int E, int nbins) {
    __shared__ int h1[MAX_BINS];
    __shared__ int sbase[MAX_BINS];
    __shared__ int s_notz;
    int tid = threadIdx.x;
    if (tid == 0) s_notz = 0;
    __syncthreads();
    if (((const int*)ei)[2 * tid + 1] != 0) s_notz = 1;
    __syncthreads();
    int is64 = (s_notz == 0);

    int blk = blockIdx.x;
    int chunk = blk * CHUNK_EDGES;
    int ss[CHUNK_EDGES / 256], dd[CHUNK_EDGES / 256];
#pragma unroll
    for (int k = 0; k < CHUNK_EDGES / 256; ++k) {
        int i = chunk + k * 256 + tid;
        dd[k] = -1;
        if (i < E) {
            if (is64) {
                ss[k] = (int)((const long long*)ei)[i];
                dd[k] = (int)((const long long*)ei)[(long long)i + E];
            } else {
                ss[k] = ((const int*)ei)[i];
                dd[k] = ((const int*)ei)[i + E];
            }
        }
    }
    for (int i = tid; i < nbins; i += 256) {
        sbase[i] = cnt[i * BSTRIDE + blk];   // scanned base (regular load)
        h1[i] = 0;
    }
    __syncthreads();
#pragma unroll
    for (int k = 0; k < CHUNK_EDGES / 256; ++k) {
        if (dd[k] >= 0) {
            int bin = dd[k] >> BIN_SHIFT;
            int r = atomicAdd(&h1[bin], 1);
            int pos = bin * BIN_CAP + sbase[bin] + r;
            if (pos < (bin + 1) * BIN_CAP)      // overflow guard (never expected)
                pairs[pos] = (ss[k] << BIN_SHIFT) | (dd[k] & (NODES_PER_BIN - 1));
        }
    }
}

// K4: fused degree + gemm.  Bin b == gemm tile b (128 nodes).  Degree
// histogram -> dinv in LDS feeds the gemm epilogue directly; deg/dinv also
// written for the aggregate epilogue.  h[r] = bf16((x[r] @ W^T) * dinv[r]).
__global__ __launch_bounds__(256) void deg_gemm_kernel(const int* __restrict__ pairs,
                                                       const int* __restrict__ bintot,
                                                       const float* __restrict__ x,
                                                       const float* __restrict__ W,
                                                       int* __restrict__ deg,
                                                       float* __restrict__ dinv,
                                                       unsigned short* __restrict__ h,
                                                       int N) {
    __shared__ float Wt[64 * 64];               // 16 KB
    __shared__ float Xs[64 * GEMM_ROWS];        // 32 KB
    __shared__ int sdeg[NODES_PER_BIN];
    __shared__ float sdinv[NODES_PER_BIN];
    int b = blockIdx.x;
    int tid = threadIdx.x;
    int node0 = b << BIN_SHIFT;
    int nn = min(NODES_PER_BIN, N - node0);
    int cntb = min(bintot[b], BIN_CAP);

    if (tid < NODES_PER_BIN) sdeg[tid] = 0;
#pragma unroll
    for (int t = 0; t < 16; ++t) {              // Wt load overlaps degree phase
        int i = t * 256 + tid;
        Wt[i] = W[((i & 63) << 6) | (i >> 6)];
    }
    __syncthreads();
    const int* pb = pairs + b * BIN_CAP;
    for (int i = tid; i < cntb; i += 256)
        atomicAdd(&sdeg[pb[i] & (NODES_PER_BIN - 1)], 1);

    const float* xbase = x + (size_t)node0 * DIM;
#pragma unroll
    for (int t = 0; t < 32; ++t) {              // Xs load (independent of degree)
        int i = t * 256 + tid;
        int r = i & (GEMM_ROWS - 1);
        int k = i >> 7;
        Xs[i] = (r < nn) ? xbase[r * DIM + k] : 0.0f;
    }
    __syncthreads();
    if (tid < NODES_PER_BIN) {
        int d = sdeg[tid];
        float dv = rsqrtf((float)(d + 1));      // +1 self-loop
        sdinv[tid] = dv;
        if (tid < nn) {
            deg[node0 + tid] = d;
            dinv[node0 + tid] = dv;
        }
    }
    __syncthreads();

    int tc = tid & 7;
    int tr = tid >> 3;
    float acc[4][8] = {};
#pragma unroll 4
    for (int k = 0; k < 64; ++k) {
        float4 xv = *(const float4*)&Xs[k * GEMM_ROWS + 4 * tr];
        float4 w0 = *(const float4*)&Wt[k * 64 + 8 * tc];
        float4 w1 = *(const float4*)&Wt[k * 64 + 8 * tc + 4];
        const float* xp = (const float*)&xv;
        const float* wp0 = (const float*)&w0;
        const float* wp1 = (const float*)&w1;
#pragma unroll
        for (int i = 0; i < 4; ++i) {
#pragma unroll
            for (int j = 0; j < 4; ++j) {
                acc[i][j] = fmaf(xp[i], wp0[j], acc[i][j]);
                acc[i][4 + j] = fmaf(xp[i], wp1[j], acc[i][4 + j]);
            }
        }
    }
#pragma unroll
    for (int i = 0; i < 4; ++i) {
        int r = 4 * tr + i;
        if (r < nn) {
            int g = node0 + r;
            float dv = sdinv[r];                // straight from LDS
            ushort4 o0, o1;
            o0.x = f2bf(acc[i][0] * dv); o0.y = f2bf(acc[i][1] * dv);
            o0.z = f2bf(acc[i][2] * dv); o0.w = f2bf(acc[i][3] * dv);
            o1.x = f2bf(acc[i][4] * dv); o1.y = f2bf(acc[i][5] * dv);
            o1.z = f2bf(acc[i][6] * dv); o1.w = f2bf(acc[i][7] * dv);
            ushort4* hp = (ushort4*)(h + (size_t)g * DIM + 8 * tc);
            hp[0] = o0;
            hp[1] = o1;
        }
    }
}

// K5: feature-split aggregate.  Block = (bin, feature-half); LDS acc 17.4 KB
// -> 8 blocks/CU (~75% occupancy) hides the random h-gather latency.
// 8-lane groups: 8 edges in flight per wave-step, 2 u64 LDS atomics per edge
// per half (0.25 wave-instr/edge).  Epilogue subtracts deg*BIAS, adds
// self-loop + bias.
__global__ __launch_bounds__(256) void aggregate_kernel(
    const unsigned short* __restrict__ h, const int* __restrict__ pairs,
    const int* __restrict__ bintot, const int* __restrict__ deg,
    const float* __restrict__ dinv, const float* __restrict__ bias,
    float* __restrict__ out, int N) {
    __shared__ unsigned long long acc[NODES_PER_BIN * AGG_STRIDE];   // 17408 B
    int blk = blockIdx.x;
    int b = blk >> 1;
    int f0 = (blk & 1) * 32;           // feature half offset
    int tid = threadIdx.x;
    int cnt = min(bintot[b], BIN_CAP);
    int node0 = b << BIN_SHIFT;
    int nn = min(NODES_PER_BIN, N - node0);

    for (int i = tid; i < NODES_PER_BIN * AGG_STRIDE; i += 256) acc[i] = 0ULL;
    __syncthreads();

    int wave = tid >> 6, lane = tid & 63;
    int g = lane >> 3;                 // edge slot 0..7
    int fq = lane & 7;                 // features f0 + 4*fq .. +3
    const int* pb = pairs + b * BIN_CAP;
    int dummy = N << BIN_SHIFT;        // src=N row exists (garbage ok, gated)

    for (int j0 = 64 * wave; j0 < cnt; j0 += 256) {
        int pk[8]; bool vd[8];
#pragma unroll
        for (int u = 0; u < 8; ++u) {
            int e = j0 + 8 * u + g;
            vd[u] = (e < cnt);
            pk[u] = vd[u] ? pb[e] : dummy;
        }
        ushort4 r[8];
#pragma unroll
        for (int u = 0; u < 8; ++u)    // issue all gathers before use
            r[u] = *(const ushort4*)(h + (size_t)(pk[u] >> BIN_SHIFT) * DIM + f0 + 4 * fq);
#pragma unroll
        for (int u = 0; u < 8; ++u) {
            unsigned q0 = __float_as_uint(fmaf(bf2f(r[u].x), FXSCALE, MAGIC)) - (MAGIC_I - FXBIAS);
            unsigned q1 = __float_as_uint(fmaf(bf2f(r[u].y), FXSCALE, MAGIC)) - (MAGIC_I - FXBIAS);
            unsigned q2 = __float_as_uint(fmaf(bf2f(r[u].z), FXSCALE, MAGIC)) - (MAGIC_I - FXBIAS);
            unsigned q3 = __float_as_uint(fmaf(bf2f(r[u].w), FXSCALE, MAGIC)) - (MAGIC_I - FXBIAS);
            if (vd[u]) {
                unsigned long long* ar =
                    &acc[(pk[u] & (NODES_PER_BIN - 1)) * AGG_STRIDE + 2 * fq];
                atomicAdd(&ar[0], (unsigned long long)q0 | ((unsigned long long)q1 << 32));
                atomicAdd(&ar[1], (unsigned long long)q2 | ((unsigned long long)q3 << 32));
            }
        }
    }
    __syncthreads();

    // dword view: feature f (0..31) of node n at dword [n*34 + f]
    const int* accd = (const int*)acc;
    int featl = tid & 31;
    float bl = bias[f0 + featl];
    for (int n0 = (tid >> 5); n0 < nn; n0 += 8) {
        int gn = node0 + n0;
        int dgn = deg[gn];
        float di = dinv[gn];
        unsigned q = (unsigned)accd[n0 * (2 * AGG_STRIDE) + featl];
        int sfx = (int)(q - (unsigned)dgn * FXBIAS);        // remove per-term bias
        float sum = (float)sfx * FXINV;
        float self = bf2f(h[(size_t)gn * DIM + f0 + featl]); // pre-scaled by dinv[gn]
        out[(size_t)gn * DIM + f0 + featl] = (sum + self) * di + bl;
    }
}

extern "C" void kernel_launch(void* const* d_in, const int* in_sizes, int n_in,
                              void* d_out, int out_size, void* d_ws, size_t ws_size,
                              hipStream_t stream) {
    const float* x = (const float*)d_in[0];
    const void* ei = d_in[1];
    const float* W = (const float*)d_in[2];
    const float* b = (const float*)d_in[3];
    float* out = (float*)d_out;

    int N = in_sizes[0] / DIM;   // 100000
    int E = in_sizes[1] / 2;     // 1000000
    int nbins = (N + NODES_PER_BIN - 1) >> BIN_SHIFT;   // 782

    char* ws = (char*)d_ws;
    auto align256 = [](size_t v) { return (v + 255) & ~(size_t)255; };
    size_t off = 0;
    int* cnt = (int*)(ws + off);       off = align256(off + (size_t)MAX_BINS * BSTRIDE * 4);
    int* bintot = (int*)(ws + off);    off = align256(off + (size_t)MAX_BINS * 4);
    int* deg = (int*)(ws + off);       off = align256(off + (size_t)(N + 1) * 4);
    float* dinv = (float*)(ws + off);  off = align256(off + (size_t)(N + 1) * 4);
    int* pairs = (int*)(ws + off);     off = align256(off + ((size_t)nbins * BIN_CAP + 64) * 4);
    unsigned short* h = (unsigned short*)(ws + off); off = align256(off + (size_t)(N + 1) * DIM * 2);

    int nchunks = (E + CHUNK_EDGES - 1) / CHUNK_EDGES;       // 977

    count_kernel<<<nchunks, 256, 0, stream>>>(ei, cnt, E, nbins);
    scan_kernel<<<nbins, 256, 0, stream>>>(cnt, bintot, nchunks);
    place_kernel<<<nchunks, 256, 0, stream>>>(ei, cnt, pairs, E, nbins);
    deg_gemm_kernel<<<nbins, 256, 0, stream>>>(pairs, bintot, x, W, deg, dinv, h, N);
    aggregate_kernel<<<2 * nbins, 256, 0, stream>>>(h, pairs, bintot, deg, dinv, b, out, N);
}

// Round 6
// 172.864 us; speedup vs baseline: 1.5308x; 1.0338x over previous
//
#include <hip/hip_runtime.h>

#define DIM 64
#define BIN_SHIFT 7                  // 128 nodes per bin
#define NODES_PER_BIN 128
#define MAX_BINS 1024                // ceil(100000/128)=782 <= 1024
#define BIN_CAP 2048                 // mean 1279, sigma ~36 -> 21-sigma margin
#define CHUNK_EDGES 2048             // edges per scatter block (R0-proven best)
#define GEMM_ROWS 128                // rows per gemm block
#define FXSCALE 65536.0f             // fixed-point scale 2^16
#define FXINV (1.0f / 65536.0f)
#define FXBIAS 524288u               // 2^19 per-term bias (|v|<8 -> term >= 0)
#define MAGIC 12582912.0f            // 1.5*2^23 RNE float->int magic
#define MAGIC_I 0x4B400000u
#define AGG_STRIDE 17                // u64 per node row: 16 used + 1 pad

// ws layout (256-aligned):
// flag | gcur[MAX_BINS] | deg[N+1] | dinv[N+1] | pairs[nbins*BIN_CAP+64] |
// h[(N+1)*64] bf16   (h row N never written; aggregate gates dummy lanes)
//
// Pipeline (5 dispatches):
//   K0 init: zero gcur + int64 detect
//   K1 scatter: R0-proven bin scatter (LDS histogram + one reservation/bin)
//   K2 degree: per-bin histogram -> deg, dinv
//   K3 gemm: 32 KB LDS (Xs in two 32-k halves) -> 5 blocks/CU
//   K4 aggregate: feature-split, u64-packed biased fixed-point LDS atomics

__device__ __forceinline__ unsigned short f2bf(float f) {
    unsigned u = __float_as_uint(f);
    u += 0x7fffu + ((u >> 16) & 1u);     // round-to-nearest-even
    return (unsigned short)(u >> 16);
}
__device__ __forceinline__ float bf2f(unsigned short u) {
    return __uint_as_float((unsigned)u << 16);
}

// K0: zero gcur, int64-vs-int32 edge detect.
__global__ __launch_bounds__(256) void init_kernel(const int* __restrict__ ei32,
                                                   int* __restrict__ flag,
                                                   int* __restrict__ gcur) {
    __shared__ int any_nz;
    int tid = threadIdx.x;
    if (tid == 0) any_nz = 0;
    __syncthreads();
    int v = ei32[2 * tid + 1];     // odd int32 words: all-zero iff nonneg int64 data
    if (v != 0) atomicOr(&any_nz, 1);
    for (int i = tid; i < MAX_BINS; i += 256) gcur[i] = 0;
    __syncthreads();
    if (tid == 0) *flag = (any_nz == 0) ? 1 : 0;
}

// K1: scatter packed (src<<7 | dst&127) into dst-bins.  R0-proven shape:
// one reservation atomic per (block,bin); contiguous write runs.
__global__ __launch_bounds__(256) void bin_scatter_kernel(const void* __restrict__ ei,
                                                          const int* __restrict__ flagp,
                                                          int* __restrict__ gcur,
                                                          int* __restrict__ pairs,
                                                          int E, int nbins) {
    __shared__ int h1[MAX_BINS];
    __shared__ int base[MAX_BINS];
    int tid = threadIdx.x;
    int is64 = *flagp;
    int chunk = blockIdx.x * CHUNK_EDGES;

    int ss[CHUNK_EDGES / 256], dd[CHUNK_EDGES / 256];

    for (int i = tid; i < nbins; i += 256) h1[i] = 0;
    __syncthreads();
#pragma unroll
    for (int k = 0; k < CHUNK_EDGES / 256; ++k) {
        int i = chunk + k * 256 + tid;
        if (i < E) {
            int s, d;
            if (is64) {
                s = (int)((const long long*)ei)[i];
                d = (int)((const long long*)ei)[(long long)i + E];
            } else {
                s = ((const int*)ei)[i];
                d = ((const int*)ei)[i + E];
            }
            ss[k] = s; dd[k] = d;
            atomicAdd(&h1[d >> BIN_SHIFT], 1);
        } else {
            dd[k] = -1;
        }
    }
    __syncthreads();
    for (int i = tid; i < nbins; i += 256) {
        int c = h1[i];
        base[i] = c ? (i * BIN_CAP + atomicAdd(&gcur[i], c)) : 0;
        h1[i] = 0;
    }
    __syncthreads();
#pragma unroll
    for (int k = 0; k < CHUNK_EDGES / 256; ++k) {
        if (dd[k] >= 0) {
            int bin = dd[k] >> BIN_SHIFT;
            int r = atomicAdd(&h1[bin], 1);
            int pos = base[bin] + r;
            if (pos < (bin + 1) * BIN_CAP)          // overflow guard (never expected)
                pairs[pos] = (ss[k] << BIN_SHIFT) | (dd[k] & (NODES_PER_BIN - 1));
        }
    }
}

// K2: per-bin degree histogram -> deg + dinv.
__global__ __launch_bounds__(256) void degree_kernel(const int* __restrict__ pairs,
                                                     const int* __restrict__ gcur,
                                                     int* __restrict__ deg,
                                                     float* __restrict__ dinv, int N) {
    __shared__ int sdeg[NODES_PER_BIN];
    int b = blockIdx.x;
    int tid = threadIdx.x;
    int base = b * BIN_CAP;
    int cnt = min(gcur[b], BIN_CAP);
    int node0 = b << BIN_SHIFT;
    int nn = min(NODES_PER_BIN, N - node0);
    if (tid < NODES_PER_BIN) sdeg[tid] = 0;
    __syncthreads();
    for (int i = tid; i < cnt; i += 256)
        atomicAdd(&sdeg[pairs[base + i] & (NODES_PER_BIN - 1)], 1);
    __syncthreads();
    if (tid < nn) {
        int d = sdeg[tid];
        deg[node0 + tid] = d;
        dinv[node0 + tid] = rsqrtf((float)(d + 1));   // +1 self-loop
    }
}

// K3: h[r] = bf16( (x[r] @ W^T) * dinv[r] ).  128x64 tile, thread = 4 rows x
// 8 cols; Xs staged in two 32-k halves -> 32 KB LDS -> 5 blocks/CU (was 3 at
// 48 KB; R5 measured the 50 KB fused variant at 21% occupancy / 44 us).
__global__ __launch_bounds__(256) void gemm_kernel(const float* __restrict__ x,
                                                   const float* __restrict__ W,
                                                   const float* __restrict__ dinv,
                                                   unsigned short* __restrict__ h, int N) {
    __shared__ float Wt[64 * 64];               // 16 KB, Wt[k*64+c]
    __shared__ float Xs[32 * GEMM_ROWS];        // 16 KB, Xs[kl*128+r]
    int tid = threadIdx.x;
    int row0 = blockIdx.x * GEMM_ROWS;
    int nrows = min(GEMM_ROWS, N - row0);
#pragma unroll
    for (int t = 0; t < 16; ++t) {
        int i = t * 256 + tid;
        Wt[i] = W[((i & 63) << 6) | (i >> 6)];   // Wt[k*64+c] = W[c*64+k]
    }
    const float* xbase = x + (size_t)row0 * DIM;
    int tc = tid & 7;
    int tr = tid >> 3;
    float acc[4][8] = {};
#pragma unroll
    for (int kh = 0; kh < 2; ++kh) {
        __syncthreads();   // kh=0: Wt visible; kh=1: prior compute done reading Xs
#pragma unroll
        for (int t = 0; t < 16; ++t) {
            int i = t * 256 + tid;                 // i = kl*128 + r
            int r = i & (GEMM_ROWS - 1);
            int k = (i >> 7) + 32 * kh;
            Xs[i] = (r < nrows) ? xbase[r * DIM + k] : 0.0f;
        }
        __syncthreads();
#pragma unroll 4
        for (int kl = 0; kl < 32; ++kl) {
            int k = kl + 32 * kh;
            float4 xv = *(const float4*)&Xs[kl * GEMM_ROWS + 4 * tr];
            float4 w0 = *(const float4*)&Wt[k * 64 + 8 * tc];
            float4 w1 = *(const float4*)&Wt[k * 64 + 8 * tc + 4];
            const float* xp = (const float*)&xv;
            const float* wp0 = (const float*)&w0;
            const float* wp1 = (const float*)&w1;
#pragma unroll
            for (int i = 0; i < 4; ++i) {
#pragma unroll
                for (int j = 0; j < 4; ++j) {
                    acc[i][j] = fmaf(xp[i], wp0[j], acc[i][j]);
                    acc[i][4 + j] = fmaf(xp[i], wp1[j], acc[i][4 + j]);
                }
            }
        }
    }
#pragma unroll
    for (int i = 0; i < 4; ++i) {
        int r = 4 * tr + i;
        if (r < nrows) {
            int g = row0 + r;
            float dv = dinv[g];
            ushort4 o0, o1;
            o0.x = f2bf(acc[i][0] * dv); o0.y = f2bf(acc[i][1] * dv);
            o0.z = f2bf(acc[i][2] * dv); o0.w = f2bf(acc[i][3] * dv);
            o1.x = f2bf(acc[i][4] * dv); o1.y = f2bf(acc[i][5] * dv);
            o1.z = f2bf(acc[i][6] * dv); o1.w = f2bf(acc[i][7] * dv);
            ushort4* hp = (ushort4*)(h + (size_t)g * DIM + 8 * tc);
            hp[0] = o0;
            hp[1] = o1;
        }
    }
}

// K4: feature-split aggregate.  Block = (bin, feature-half); 17.4 KB LDS ->
// 8 blocks/CU hides the random h-gather latency.  2 features per ds_add_u64
// with +2^19 per-term bias; epilogue subtracts deg*BIAS, adds self-loop+bias.
__global__ __launch_bounds__(256) void aggregate_kernel(
    const unsigned short* __restrict__ h, const int* __restrict__ pairs,
    const int* __restrict__ gcur, const int* __restrict__ deg,
    const float* __restrict__ dinv, const float* __restrict__ bias,
    float* __restrict__ out, int N) {
    __shared__ unsigned long long acc[NODES_PER_BIN * AGG_STRIDE];   // 17408 B
    int blk = blockIdx.x;
    int b = blk >> 1;
    int f0 = (blk & 1) * 32;           // feature half offset
    int tid = threadIdx.x;
    int cnt = min(gcur[b], BIN_CAP);
    int node0 = b << BIN_SHIFT;
    int nn = min(NODES_PER_BIN, N - node0);

    for (int i = tid; i < NODES_PER_BIN * AGG_STRIDE; i += 256) acc[i] = 0ULL;
    __syncthreads();

    int wave = tid >> 6, lane = tid & 63;
    int g = lane >> 3;                 // edge slot 0..7
    int fq = lane & 7;                 // features f0 + 4*fq .. +3
    const int* pb = pairs + b * BIN_CAP;
    int dummy = N << BIN_SHIFT;        // row N load is garbage but gated off

    for (int j0 = 64 * wave; j0 < cnt; j0 += 256) {
        int pk[8]; bool vd[8];
#pragma unroll
        for (int u = 0; u < 8; ++u) {
            int e = j0 + 8 * u + g;
            vd[u] = (e < cnt);
            pk[u] = vd[u] ? pb[e] : dummy;
        }
        ushort4 r[8];
#pragma unroll
        for (int u = 0; u < 8; ++u)    // issue all gathers before use
            r[u] = *(const ushort4*)(h + (size_t)(pk[u] >> BIN_SHIFT) * DIM + f0 + 4 * fq);
#pragma unroll
        for (int u = 0; u < 8; ++u) {
            unsigned q0 = __float_as_uint(fmaf(bf2f(r[u].x), FXSCALE, MAGIC)) - (MAGIC_I - FXBIAS);
            unsigned q1 = __float_as_uint(fmaf(bf2f(r[u].y), FXSCALE, MAGIC)) - (MAGIC_I - FXBIAS);
            unsigned q2 = __float_as_uint(fmaf(bf2f(r[u].z), FXSCALE, MAGIC)) - (MAGIC_I - FXBIAS);
            unsigned q3 = __float_as_uint(fmaf(bf2f(r[u].w), FXSCALE, MAGIC)) - (MAGIC_I - FXBIAS);
            if (vd[u]) {
                unsigned long long* ar =
                    &acc[(pk[u] & (NODES_PER_BIN - 1)) * AGG_STRIDE + 2 * fq];
                atomicAdd(&ar[0], (unsigned long long)q0 | ((unsigned long long)q1 << 32));
                atomicAdd(&ar[1], (unsigned long long)q2 | ((unsigned long long)q3 << 32));
            }
        }
    }
    __syncthreads();

    // dword view: feature f (0..31) of node n at dword [n*34 + f]
    const int* accd = (const int*)acc;
    int featl = tid & 31;
    float bl = bias[f0 + featl];
    for (int n0 = (tid >> 5); n0 < nn; n0 += 8) {
        int gn = node0 + n0;
        int dgn = deg[gn];
        float di = dinv[gn];
        unsigned q = (unsigned)accd[n0 * (2 * AGG_STRIDE) + featl];
        int sfx = (int)(q - (unsigned)dgn * FXBIAS);        // remove per-term bias
        float sum = (float)sfx * FXINV;
        float self = bf2f(h[(size_t)gn * DIM + f0 + featl]); // pre-scaled by dinv[gn]
        out[(size_t)gn * DIM + f0 + featl] = (sum + self) * di + bl;
    }
}

extern "C" void kernel_launch(void* const* d_in, const int* in_sizes, int n_in,
                              void* d_out, int out_size, void* d_ws, size_t ws_size,
                              hipStream_t stream) {
    const float* x = (const float*)d_in[0];
    const void* ei = d_in[1];
    const float* W = (const float*)d_in[2];
    const float* b = (const float*)d_in[3];
    float* out = (float*)d_out;

    int N = in_sizes[0] / DIM;   // 100000
    int E = in_sizes[1] / 2;     // 1000000
    int nbins = (N + NODES_PER_BIN - 1) >> BIN_SHIFT;   // 782

    char* ws = (char*)d_ws;
    auto align256 = [](size_t v) { return (v + 255) & ~(size_t)255; };
    size_t off = 0;
    int* flag = (int*)(ws + off);              off = align256(off + 4);
    int* gcur = (int*)(ws + off);              off = align256(off + (size_t)MAX_BINS * 4);
    int* deg  = (int*)(ws + off);              off = align256(off + (size_t)(N + 1) * 4);
    float* dinv = (float*)(ws + off);          off = align256(off + (size_t)(N + 1) * 4);
    int* pairs = (int*)(ws + off);             off = align256(off + ((size_t)nbins * BIN_CAP + 64) * 4);
    unsigned short* h = (unsigned short*)(ws + off); off = align256(off + (size_t)(N + 1) * DIM * 2);

    int nchunks = (E + CHUNK_EDGES - 1) / CHUNK_EDGES;       // 489
    int gemmblocks = (N + GEMM_ROWS - 1) / GEMM_ROWS;        // 782

    init_kernel<<<1, 256, 0, stream>>>((const int*)ei, flag, gcur);
    bin_scatter_kernel<<<nchunks, 256, 0, stream>>>(ei, flag, gcur, pairs, E, nbins);
    degree_kernel<<<nbins, 256, 0, stream>>>(pairs, gcur, deg, dinv, N);
    gemm_kernel<<<gemmblocks, 256, 0, stream>>>(x, W, dinv, h, N);
    aggregate_kernel<<<2 * nbins, 256, 0, stream>>>(h, pairs, gcur, deg, dinv, b, out, N);
}

// Round 7
// 151.175 us; speedup vs baseline: 1.7504x; 1.1435x over previous
//
#include <hip/hip_runtime.h>

#define DIM 64
#define BIN_SHIFT 7                  // 128 nodes per bin
#define NODES_PER_BIN 128
#define MAX_BINS 1024                // ceil(100000/128)=782 <= 1024
#define BIN_CAP 2048                 // mean 1279, sigma ~36 -> 21-sigma margin
#define CHUNK_EDGES 2048             // edges per scatter block (R0-proven best)
#define GEMM_ROWS 128                // rows per gemm block
#define FXSCALE 65536.0f             // fixed-point scale 2^16
#define FXINV (1.0f / 65536.0f)
#define FXBIAS 524288u               // 2^19 per-term bias (|v|<8 -> term >= 0)
#define MAGIC 12582912.0f            // 1.5*2^23 RNE float->int magic
#define MAGIC_I 0x4B400000u
#define AGG_STRIDE 17                // u64 per node row: 16 used + 1 pad

// ws layout (256-aligned):
// gcur[MAX_BINS] | deg[N+1] | dinv[N+1] | pairs[nbins*BIN_CAP+64] | h[(N+1)*64] bf16
//
// Pipeline (1 memset + 4 dispatches):
//   memset gcur
//   K1 scatter: R0-proven bin scatter (per-block is64 detect, LDS hist + reservation)
//   K2 degree: per-bin histogram -> deg, dinv
//   K3 gemm: MFMA bf16 16x16x32, swizzled LDS frags, 25 KB -> 6 blocks/CU
//   K4 aggregate: feature-split, u64-packed biased fixed-point LDS atomics

using bf16x8 = __attribute__((ext_vector_type(8))) short;
using f32x4  = __attribute__((ext_vector_type(4))) float;

__device__ __forceinline__ unsigned short f2bf(float f) {
    unsigned u = __float_as_uint(f);
    u += 0x7fffu + ((u >> 16) & 1u);     // round-to-nearest-even
    return (unsigned short)(u >> 16);
}
__device__ __forceinline__ float bf2f(unsigned short u) {
    return __uint_as_float((unsigned)u << 16);
}

// K1: scatter packed (src<<7 | dst&127) into dst-bins.  R0-proven shape:
// one reservation atomic per (block,bin); contiguous write runs.  is64
// detection replicated per block (first 256 odd int32 words, L2-hot).
__global__ __launch_bounds__(256) void bin_scatter_kernel(const void* __restrict__ ei,
                                                          int* __restrict__ gcur,
                                                          int* __restrict__ pairs,
                                                          int E, int nbins) {
    __shared__ int h1[MAX_BINS];
    __shared__ int base[MAX_BINS];
    __shared__ int s_notz;
    int tid = threadIdx.x;
    if (tid == 0) s_notz = 0;
    for (int i = tid; i < nbins; i += 256) h1[i] = 0;
    __syncthreads();
    if (((const int*)ei)[2 * tid + 1] != 0) s_notz = 1;   // benign race (same value)
    __syncthreads();
    int is64 = (s_notz == 0);
    int chunk = blockIdx.x * CHUNK_EDGES;

    int ss[CHUNK_EDGES / 256], dd[CHUNK_EDGES / 256];
#pragma unroll
    for (int k = 0; k < CHUNK_EDGES / 256; ++k) {
        int i = chunk + k * 256 + tid;
        if (i < E) {
            int s, d;
            if (is64) {
                s = (int)((const long long*)ei)[i];
                d = (int)((const long long*)ei)[(long long)i + E];
            } else {
                s = ((const int*)ei)[i];
                d = ((const int*)ei)[i + E];
            }
            ss[k] = s; dd[k] = d;
            atomicAdd(&h1[d >> BIN_SHIFT], 1);
        } else {
            dd[k] = -1;
        }
    }
    __syncthreads();
    for (int i = tid; i < nbins; i += 256) {
        int c = h1[i];
        base[i] = c ? (i * BIN_CAP + atomicAdd(&gcur[i], c)) : 0;
        h1[i] = 0;
    }
    __syncthreads();
#pragma unroll
    for (int k = 0; k < CHUNK_EDGES / 256; ++k) {
        if (dd[k] >= 0) {
            int bin = dd[k] >> BIN_SHIFT;
            int r = atomicAdd(&h1[bin], 1);
            int pos = base[bin] + r;
            if (pos < (bin + 1) * BIN_CAP)          // overflow guard (never expected)
                pairs[pos] = (ss[k] << BIN_SHIFT) | (dd[k] & (NODES_PER_BIN - 1));
        }
    }
}

// K2: per-bin degree histogram -> deg + dinv.
__global__ __launch_bounds__(256) void degree_kernel(const int* __restrict__ pairs,
                                                     const int* __restrict__ gcur,
                                                     int* __restrict__ deg,
                                                     float* __restrict__ dinv, int N) {
    __shared__ int sdeg[NODES_PER_BIN];
    int b = blockIdx.x;
    int tid = threadIdx.x;
    int base = b * BIN_CAP;
    int cnt = min(gcur[b], BIN_CAP);
    int node0 = b << BIN_SHIFT;
    int nn = min(NODES_PER_BIN, N - node0);
    if (tid < NODES_PER_BIN) sdeg[tid] = 0;
    __syncthreads();
    for (int i = tid; i < cnt; i += 256)
        atomicAdd(&sdeg[pairs[base + i] & (NODES_PER_BIN - 1)], 1);
    __syncthreads();
    if (tid < nn) {
        int d = sdeg[tid];
        deg[node0 + tid] = d;
        dinv[node0 + tid] = rsqrtf((float)(d + 1));   // +1 self-loop
    }
}

// K3: MFMA gemm.  h[r] = bf16( (x[r] @ W^T) * dinv[r] ).
// Block = 128 rows x 64 cols, 4 waves; wave w owns rows 32w..32w+31
// (2 m-tiles x 4 n-tiles of 16x16), K=64 in 2 mfma_16x16x32 steps.
// Frag layout: A[m][k] m=lane&15 k=(lane>>4)*8+j; B[k][n]=W[n][k] n=lane&15;
// D: col=lane&15, row=(lane>>4)*4+reg (HW-verified mapping).
// LDS tiles XOR-swizzled (byte ^= (row&7)<<4) to break the stride-128B
// 16-way bank conflict on ds_read_b128 fragment loads.
__global__ __launch_bounds__(256) void gemm_kernel(const float* __restrict__ x,
                                                   const float* __restrict__ W,
                                                   const float* __restrict__ dinv,
                                                   unsigned short* __restrict__ h, int N) {
    __shared__ unsigned short Xs[GEMM_ROWS * 64];   // 16 KB, swizzled [row][k] bf16
    __shared__ unsigned short Ws[64 * 64];          // 8 KB,  swizzled [n][k]  bf16
    __shared__ float sdinv[GEMM_ROWS];
    int tid = threadIdx.x;
    int row0 = blockIdx.x * GEMM_ROWS;
    int nn = min(GEMM_ROWS, N - row0);

    // stage W (64x64 fp32 -> bf16), 2 x 16B writes per thread
#pragma unroll
    for (int u = 0; u < 2; ++u) {
        int idx = u * 256 + tid;
        int c = idx >> 3, k0 = (idx & 7) * 8;
        float4 a = *(const float4*)&W[c * 64 + k0];
        float4 b = *(const float4*)&W[c * 64 + k0 + 4];
        bf16x8 v;
        v[0] = (short)f2bf(a.x); v[1] = (short)f2bf(a.y);
        v[2] = (short)f2bf(a.z); v[3] = (short)f2bf(a.w);
        v[4] = (short)f2bf(b.x); v[5] = (short)f2bf(b.y);
        v[6] = (short)f2bf(b.z); v[7] = (short)f2bf(b.w);
        int byteoff = c * 128 + ((k0 * 2) ^ ((c & 7) << 4));
        *(bf16x8*)((char*)Ws + byteoff) = v;
    }
    // stage X (128x64 fp32 -> bf16), 4 x 16B writes per thread
    const float* xbase = x + (size_t)row0 * DIM;
#pragma unroll
    for (int u = 0; u < 4; ++u) {
        int idx = u * 256 + tid;
        int r = idx >> 3, k0 = (idx & 7) * 8;
        float4 a = make_float4(0.f, 0.f, 0.f, 0.f), b = a;
        if (r < nn) {
            a = *(const float4*)&xbase[r * DIM + k0];
            b = *(const float4*)&xbase[r * DIM + k0 + 4];
        }
        bf16x8 v;
        v[0] = (short)f2bf(a.x); v[1] = (short)f2bf(a.y);
        v[2] = (short)f2bf(a.z); v[3] = (short)f2bf(a.w);
        v[4] = (short)f2bf(b.x); v[5] = (short)f2bf(b.y);
        v[6] = (short)f2bf(b.z); v[7] = (short)f2bf(b.w);
        int byteoff = r * 128 + ((k0 * 2) ^ ((r & 7) << 4));
        *(bf16x8*)((char*)Xs + byteoff) = v;
    }
    if (tid < GEMM_ROWS) sdinv[tid] = (tid < nn) ? dinv[row0 + tid] : 0.0f;
    __syncthreads();

    int w = tid >> 6, l = tid & 63;
    int lm = l & 15, kg = l >> 4;
    f32x4 acc[2][4] = {};
#pragma unroll
    for (int ks = 0; ks < 2; ++ks) {
        int kbyte = ks * 64 + kg * 16;
        int r0g = 32 * w + lm;
        int r1g = 32 * w + 16 + lm;
        bf16x8 a0 = *(const bf16x8*)((const char*)Xs + r0g * 128 + (kbyte ^ ((r0g & 7) << 4)));
        bf16x8 a1 = *(const bf16x8*)((const char*)Xs + r1g * 128 + (kbyte ^ ((r1g & 7) << 4)));
#pragma unroll
        for (int nt = 0; nt < 4; ++nt) {
            int ng = nt * 16 + lm;
            bf16x8 bv = *(const bf16x8*)((const char*)Ws + ng * 128 + (kbyte ^ ((ng & 7) << 4)));
            acc[0][nt] = __builtin_amdgcn_mfma_f32_16x16x32_bf16(a0, bv, acc[0][nt], 0, 0, 0);
            acc[1][nt] = __builtin_amdgcn_mfma_f32_16x16x32_bf16(a1, bv, acc[1][nt], 0, 0, 0);
        }
    }
    // epilogue: D row = (l>>4)*4 + j, col = l&15 within each 16x16 tile
#pragma unroll
    for (int mt = 0; mt < 2; ++mt) {
#pragma unroll
        for (int j = 0; j < 4; ++j) {
            int rl = 32 * w + 16 * mt + (l >> 4) * 4 + j;
            if (rl < nn) {
                float dv = sdinv[rl];
                size_t rowoff = (size_t)(row0 + rl) * DIM;
#pragma unroll
                for (int nt = 0; nt < 4; ++nt)
                    h[rowoff + nt * 16 + lm] = f2bf(acc[mt][nt][j] * dv);
            }
        }
    }
}

// K4: feature-split aggregate.  Block = (bin, feature-half); 17.4 KB LDS ->
// 8 blocks/CU hides the random h-gather latency.  2 features per ds_add_u64
// with +2^19 per-term bias; epilogue subtracts deg*BIAS, adds self-loop+bias.
__global__ __launch_bounds__(256) void aggregate_kernel(
    const unsigned short* __restrict__ h, const int* __restrict__ pairs,
    const int* __restrict__ gcur, const int* __restrict__ deg,
    const float* __restrict__ dinv, const float* __restrict__ bias,
    float* __restrict__ out, int N) {
    __shared__ unsigned long long acc[NODES_PER_BIN * AGG_STRIDE];   // 17408 B
    int blk = blockIdx.x;
    int b = blk >> 1;
    int f0 = (blk & 1) * 32;           // feature half offset
    int tid = threadIdx.x;
    int cnt = min(gcur[b], BIN_CAP);
    int node0 = b << BIN_SHIFT;
    int nn = min(NODES_PER_BIN, N - node0);

    for (int i = tid; i < NODES_PER_BIN * AGG_STRIDE; i += 256) acc[i] = 0ULL;
    __syncthreads();

    int wave = tid >> 6, lane = tid & 63;
    int g = lane >> 3;                 // edge slot 0..7
    int fq = lane & 7;                 // features f0 + 4*fq .. +3
    const int* pb = pairs + b * BIN_CAP;
    int dummy = N << BIN_SHIFT;        // row N load is garbage but gated off

    for (int j0 = 64 * wave; j0 < cnt; j0 += 256) {
        int pk[8]; bool vd[8];
#pragma unroll
        for (int u = 0; u < 8; ++u) {
            int e = j0 + 8 * u + g;
            vd[u] = (e < cnt);
            pk[u] = vd[u] ? pb[e] : dummy;
        }
        ushort4 r[8];
#pragma unroll
        for (int u = 0; u < 8; ++u)    // issue all gathers before use
            r[u] = *(const ushort4*)(h + (size_t)(pk[u] >> BIN_SHIFT) * DIM + f0 + 4 * fq);
#pragma unroll
        for (int u = 0; u < 8; ++u) {
            unsigned q0 = __float_as_uint(fmaf(bf2f(r[u].x), FXSCALE, MAGIC)) - (MAGIC_I - FXBIAS);
            unsigned q1 = __float_as_uint(fmaf(bf2f(r[u].y), FXSCALE, MAGIC)) - (MAGIC_I - FXBIAS);
            unsigned q2 = __float_as_uint(fmaf(bf2f(r[u].z), FXSCALE, MAGIC)) - (MAGIC_I - FXBIAS);
            unsigned q3 = __float_as_uint(fmaf(bf2f(r[u].w), FXSCALE, MAGIC)) - (MAGIC_I - FXBIAS);
            if (vd[u]) {
                unsigned long long* ar =
                    &acc[(pk[u] & (NODES_PER_BIN - 1)) * AGG_STRIDE + 2 * fq];
                atomicAdd(&ar[0], (unsigned long long)q0 | ((unsigned long long)q1 << 32));
                atomicAdd(&ar[1], (unsigned long long)q2 | ((unsigned long long)q3 << 32));
            }
        }
    }
    __syncthreads();

    // dword view: feature f (0..31) of node n at dword [n*34 + f]
    const int* accd = (const int*)acc;
    int featl = tid & 31;
    float bl = bias[f0 + featl];
    for (int n0 = (tid >> 5); n0 < nn; n0 += 8) {
        int gn = node0 + n0;
        int dgn = deg[gn];
        float di = dinv[gn];
        unsigned q = (unsigned)accd[n0 * (2 * AGG_STRIDE) + featl];
        int sfx = (int)(q - (unsigned)dgn * FXBIAS);        // remove per-term bias
        float sum = (float)sfx * FXINV;
        float self = bf2f(h[(size_t)gn * DIM + f0 + featl]); // pre-scaled by dinv[gn]
        out[(size_t)gn * DIM + f0 + featl] = (sum + self) * di + bl;
    }
}

extern "C" void kernel_launch(void* const* d_in, const int* in_sizes, int n_in,
                              void* d_out, int out_size, void* d_ws, size_t ws_size,
                              hipStream_t stream) {
    const float* x = (const float*)d_in[0];
    const void* ei = d_in[1];
    const float* W = (const float*)d_in[2];
    const float* b = (const float*)d_in[3];
    float* out = (float*)d_out;

    int N = in_sizes[0] / DIM;   // 100000
    int E = in_sizes[1] / 2;     // 1000000
    int nbins = (N + NODES_PER_BIN - 1) >> BIN_SHIFT;   // 782

    char* ws = (char*)d_ws;
    auto align256 = [](size_t v) { return (v + 255) & ~(size_t)255; };
    size_t off = 0;
    int* gcur = (int*)(ws + off);              off = align256(off + (size_t)MAX_BINS * 4);
    int* deg  = (int*)(ws + off);              off = align256(off + (size_t)(N + 1) * 4);
    float* dinv = (float*)(ws + off);          off = align256(off + (size_t)(N + 1) * 4);
    int* pairs = (int*)(ws + off);             off = align256(off + ((size_t)nbins * BIN_CAP + 64) * 4);
    unsigned short* h = (unsigned short*)(ws + off); off = align256(off + (size_t)(N + 1) * DIM * 2);

    int nchunks = (E + CHUNK_EDGES - 1) / CHUNK_EDGES;       // 489
    int gemmblocks = (N + GEMM_ROWS - 1) / GEMM_ROWS;        // 782

    hipMemsetAsync(gcur, 0, (size_t)MAX_BINS * 4, stream);
    bin_scatter_kernel<<<nchunks, 256, 0, stream>>>(ei, gcur, pairs, E, nbins);
    degree_kernel<<<nbins, 256, 0, stream>>>(pairs, gcur, deg, dinv, N);
    gemm_kernel<<<gemmblocks, 256, 0, stream>>>(x, W, dinv, h, N);
    aggregate_kernel<<<2 * nbins, 256, 0, stream>>>(h, pairs, gcur, deg, dinv, b, out, N);
}